// Round 2
// baseline (264.572 us; speedup 1.0000x reference)
//
#include <hip/hip_runtime.h>

// CML1D: 15-step coupled map lattice, fp32, rows=2048, L=16384.
//   mapped = R*g*(1-g);  g' = c0*mapped[i-1] + c1*mapped[i] + c2*mapped[i+1] + BETA*d
//   (circular). out = clip(g, 1e-4, 1-1e-4) after 15 steps.
//
// R5: persistent waves + software-pipelined I/O on top of R4's VALU diet.
//   - Grid = 2048 blocks (exactly 8/CU resident, LDS 8*17408=139KB<160KB).
//     Each wave processes T=4 segments: gw = t*8192 + blockIdx*4 + wv.
//   - Per iteration: stage prefetch-regs->LDS, unpack to g[]/bd[], then
//     ISSUE next segment's 5 float4 loads before the 15-step compute
//     (sched_barrier pins them); ~2000 cycles of FMA hides HBM latency.
//     Single LDS slot: it is dead between unpack and store-transpose, and
//     DS ops are in-order within a wave (wave_barrier = compiler fence only).
//   - Clamp via v_med3_f32 (1 VALU instead of min+max).
//   - Compute core unchanged from R4: mh = fmaf(-g,g,g), R folded into taps,
//     boundary cells last so the 2 ds_bpermute waits are buried.

constexpr float Rc    = 3.9f;
constexpr float EPSc  = 0.3f;
constexpr float BETAc = 0.15f;
constexpr int   STEPS = 15;
constexpr int   L     = 16384;
constexpr int   CE    = 17;           // cells per lane (extended)
constexpr int   SEG   = 1024;         // valid cells per wave
constexpr int   GHOST = 32;           // ghost cells per side
constexpr int   EXT   = SEG + 2*GHOST;  // 1088
constexpr int   TPB   = 256;
constexpr int   WPB   = TPB / 64;     // 4 waves per block
constexpr int   T     = 4;            // segments per wave (persistent)
constexpr int   NBLK  = 2048;         // 32768 waves / (WPB*T)

__global__ __launch_bounds__(TPB)
void cml1d_kernel(const float* __restrict__ drive,
                  const float* __restrict__ K,
                  float* __restrict__ out) {
    __shared__ float lds[WPB][EXT];   // 4*1088*4 = 17408 B, per-wave private slots

    const int lane = threadIdx.x & 63;
    const int wv   = threadIdx.x >> 6;
    const int gw0  = blockIdx.x * WPB + wv;   // segment id for t=0; +8192 per t

    const float K0 = K[0], K1 = K[1], K2 = K[2];
    const float A  = (1.0f - BETAc) * (1.0f - EPSc);
    const float B  = (1.0f - BETAc) * EPSc;
    const float d0 = Rc * (B * K0);
    const float d1 = Rc * (A + B * K1);
    const float d2 = Rc * (B * K2);

    // ghost-exchange bpermute addresses, hoisted
    const int addrL = ((lane - 1) & 63) << 2;
    const int addrR = ((lane + 1) & 63) << 2;

    // ---- prime the pipeline: prefetch segment t=0 into registers ----
    float4 p[5];
    {
        const int gw  = gw0;
        const int row = gw >> 4, seg = gw & 15;
        const size_t rb = (size_t)row * L;
        const int wbase = seg * SEG - GHOST;
        #pragma unroll
        for (int j = 0; j < 5; ++j) {
            int f = j * 64 + lane;
            if (f < EXT / 4) {
                int idx = (wbase + f * 4) & (L - 1);   // window wrap, float4-safe
                p[j] = *reinterpret_cast<const float4*>(drive + rb + idx);
            }
        }
    }

    #pragma unroll 1
    for (int t = 0; t < T; ++t) {
        const int gw  = t * (NBLK * WPB) + gw0;
        const int row = gw >> 4, seg = gw & 15;
        const size_t rb = (size_t)row * L;

        // ---- stage prefetched registers -> LDS (coalesced layout) ----
        #pragma unroll
        for (int j = 0; j < 5; ++j) {
            int f = j * 64 + lane;
            if (f < EXT / 4)
                *reinterpret_cast<float4*>(&lds[wv][f * 4]) = p[j];
        }
        __builtin_amdgcn_wave_barrier();   // ds_write before ds_read, program order

        // ---- LDS -> registers: lane's 17 contiguous cells (stride 17) ----
        float g[CE], bd[CE];
        #pragma unroll
        for (int i = 0; i < CE; ++i) {
            float v = lds[wv][lane * CE + i];
            g[i]  = v;
            bd[i] = BETAc * v;
        }

        // ---- issue NEXT segment's global loads; they fly under the compute ----
        if (t < T - 1) {
            const int gw2  = (t + 1) * (NBLK * WPB) + gw0;
            const int row2 = gw2 >> 4, seg2 = gw2 & 15;
            const size_t rb2 = (size_t)row2 * L;
            const int wb2 = seg2 * SEG - GHOST;
            #pragma unroll
            for (int j = 0; j < 5; ++j) {
                int f = j * 64 + lane;
                if (f < EXT / 4) {
                    int idx = (wb2 + f * 4) & (L - 1);
                    p[j] = *reinterpret_cast<const float4*>(drive + rb2 + idx);
                }
            }
        }
        __builtin_amdgcn_sched_barrier(0); // pin load issue before the compute loop

        // ---- 15 steps, register-only, no barriers ----
        for (int s = 0; s < STEPS; ++s) {
            float mh0  = fmaf(-g[0],      g[0],      g[0]);        // g - g^2
            float mhT  = fmaf(-g[CE - 1], g[CE - 1], g[CE - 1]);
            float mleft  = __int_as_float(
                __builtin_amdgcn_ds_bpermute(addrL, __float_as_int(mhT)));
            float mright = __int_as_float(
                __builtin_amdgcn_ds_bpermute(addrR, __float_as_int(mh0)));

            float mprev = mh0;
            float mcur  = fmaf(-g[1], g[1], g[1]);
            const float m1s = mcur;                 // mh[1], for i=0 later
            float mTs = mcur;                       // becomes mh[CE-2]
            #pragma unroll
            for (int i = 1; i < CE - 1; ++i) {
                float mnext;
                if (i == CE - 2) { mnext = mhT; mTs = mcur; }
                else {
                    float gv = g[i + 1];
                    mnext = fmaf(-gv, gv, gv);
                }
                g[i] = fmaf(d0, mprev, fmaf(d1, mcur, fmaf(d2, mnext, bd[i])));
                mprev = mcur;
                mcur  = mnext;
            }
            g[0]      = fmaf(d0, mleft, fmaf(d1, mh0, fmaf(d2, m1s,    bd[0])));
            g[CE - 1] = fmaf(d0, mTs,   fmaf(d1, mhT, fmaf(d2, mright, bd[CE - 1])));
        }

        // ---- registers -> LDS -> coalesced float4 stores (slot is dead now) ----
        __builtin_amdgcn_wave_barrier();
        #pragma unroll
        for (int i = 0; i < CE; ++i) lds[wv][lane * CE + i] = g[i];
        __builtin_amdgcn_wave_barrier();

        const float lo = 0.0001f;
        const float hi = 0.9999f;   // float(1.0 - 0.0001)
        #pragma unroll
        for (int j = 0; j < 4; ++j) {
            int f = j * 64 + lane;                    // 256 float4 = 1024 floats
            float4 v = *reinterpret_cast<float4*>(&lds[wv][GHOST + f * 4]);
            v.x = __builtin_amdgcn_fmed3f(v.x, lo, hi);
            v.y = __builtin_amdgcn_fmed3f(v.y, lo, hi);
            v.z = __builtin_amdgcn_fmed3f(v.z, lo, hi);
            v.w = __builtin_amdgcn_fmed3f(v.w, lo, hi);
            *reinterpret_cast<float4*>(out + rb + seg * SEG + f * 4) = v;
        }
        __builtin_amdgcn_wave_barrier();   // store-phase reads before next stage writes
    }
}

extern "C" void kernel_launch(void* const* d_in, const int* in_sizes, int n_in,
                              void* d_out, int out_size, void* d_ws, size_t ws_size,
                              hipStream_t stream) {
    const float* drive = (const float*)d_in[0];
    const float* K     = (const float*)d_in[1];
    float* out         = (float*)d_out;
    cml1d_kernel<<<dim3(NBLK), dim3(TPB), 0, stream>>>(drive, K, out);
}

// Round 3
// 236.874 us; speedup vs baseline: 1.1169x; 1.1169x over previous
//
#include <hip/hip_runtime.h>
#include <stdint.h>

// CML1D: 15-step coupled map lattice, fp32, rows=2048, L=16384.
//   mapped = R*g*(1-g);  g' = c0*mapped[i-1] + c1*mapped[i] + c2*mapped[i+1] + BETA*d
//   (circular). out = clip(g, 1e-4, 1-1e-4) after 15 steps.
//
// R6: persistent waves + LDS-DMA prefetch (fixes R5's scratch spill).
//   - R5 post-mortem: register prefetch (p[20]) pushed the live set to ~63
//     VGPRs; allocator spilled to scratch -> +190MB HBM traffic, 113us.
//   - Fix: prefetch via __builtin_amdgcn_global_load_lds (zero VGPRs held).
//     Staging layout is exactly the HW pattern: dest = uniform base + lane*16.
//     Per segment: 4x width-16 rounds (1024 floats) + 1x width-4 tail (64).
//   - Double-buffered per-wave LDS slots (2 x 1088 floats): DMA fills buf B
//     while buf A (dead after unpack) serves the store-transpose.
//     LDS/block = 34816 B -> 4 blocks/CU, 16 waves/CU; async prefetch makes
//     that sufficient (no wave ever waits on HBM in steady state).
//   - vmcnt(4) before unpack: vmcnt retires in issue order, so <=4
//     outstanding => the 5 older prefetch loads are done; the 4 newer output
//     stores stay in flight (never drain to 0 mid-loop).
//   - Compute core unchanged from R4: mh = fmaf(-g,g,g), R folded into taps,
//     boundary cells last so the 2 ds_bpermute waits are buried.

constexpr float Rc    = 3.9f;
constexpr float EPSc  = 0.3f;
constexpr float BETAc = 0.15f;
constexpr int   STEPS = 15;
constexpr int   L     = 16384;
constexpr int   CE    = 17;             // cells per lane (extended)
constexpr int   SEG   = 1024;           // valid cells per wave
constexpr int   GHOST = 32;             // ghost cells per side (>15 steps)
constexpr int   EXT   = SEG + 2*GHOST;  // 1088 = 64*CE
constexpr int   TPB   = 256;
constexpr int   WPB   = TPB / 64;       // 4 waves per block
constexpr int   NBLK  = 1024;           // 4 blocks/CU resident (LDS-capped)

typedef const __attribute__((address_space(1))) float gfloat;
typedef __attribute__((address_space(3))) float lfloat;

__global__ __launch_bounds__(TPB)
void cml1d_kernel(const float* __restrict__ drive,
                  const float* __restrict__ K,
                  float* __restrict__ out,
                  int T) {
    __shared__ float lds[WPB][2][EXT];   // 4*2*1088*4 = 34816 B

    const int lane = threadIdx.x & 63;
    const int wv   = threadIdx.x >> 6;
    const int gw0  = blockIdx.x * WPB + wv;   // wave-segment id; +4096 per t

    const float K0 = K[0], K1 = K[1], K2 = K[2];
    const float A  = (1.0f - BETAc) * (1.0f - EPSc);
    const float B  = (1.0f - BETAc) * EPSc;
    const float d0 = Rc * (B * K0);
    const float d1 = Rc * (A + B * K1);
    const float d2 = Rc * (B * K2);

    const int addrL = ((lane - 1) & 63) << 2;   // ghost-exchange bpermute addrs
    const int addrR = ((lane + 1) & 63) << 2;

    float g[CE], bd[CE];

    // async DMA: one segment's extended window -> LDS buf (holds no VGPRs)
    auto prefetch = [&](int gw, float* buf) {
        const int row = gw >> 4, seg = gw & 15;
        const float* base = drive + (size_t)row * L;
        const int wb = seg * SEG - GHOST;            // multiple of 32 -> wrap f4-safe
        #pragma unroll
        for (int j = 0; j < 4; ++j) {                // dest: j*1024B + lane*16B
            int idx = (wb + j * 256 + lane * 4) & (L - 1);
            __builtin_amdgcn_global_load_lds((gfloat*)(base + idx),
                                             (lfloat*)(buf + j * 256), 16, 0, 0);
        }
        int idx = (wb + 1024 + lane) & (L - 1);      // tail 64 floats, width 4
        __builtin_amdgcn_global_load_lds((gfloat*)(base + idx),
                                         (lfloat*)(buf + 1024), 4, 0, 0);
    };
    auto unpack = [&](const float* buf) {            // lane's 17 contiguous cells
        #pragma unroll
        for (int i = 0; i < CE; ++i) {
            float v = buf[lane * CE + i];
            g[i]  = v;
            bd[i] = BETAc * v;
        }
    };

    // ---- prime the pipeline ----
    prefetch(gw0, &lds[wv][0][0]);
    asm volatile("s_waitcnt vmcnt(0)" ::: "memory");
    unpack(&lds[wv][0][0]);

    int cur = 0;
    #pragma unroll 1
    for (int t = 0; t < T; ++t) {
        // issue next segment's DMA into the other buffer; flies under compute
        if (t < T - 1)
            prefetch((t + 1) * (NBLK * WPB) + gw0, &lds[wv][cur ^ 1][0]);
        __builtin_amdgcn_sched_barrier(0);   // pin DMA issue before compute

        // ---- 15 steps, register-only, no barriers ----
        for (int s = 0; s < STEPS; ++s) {
            float mh0  = fmaf(-g[0],      g[0],      g[0]);        // g - g^2
            float mhT  = fmaf(-g[CE - 1], g[CE - 1], g[CE - 1]);
            float mleft  = __int_as_float(
                __builtin_amdgcn_ds_bpermute(addrL, __float_as_int(mhT)));
            float mright = __int_as_float(
                __builtin_amdgcn_ds_bpermute(addrR, __float_as_int(mh0)));

            float mprev = mh0;
            float mcur  = fmaf(-g[1], g[1], g[1]);
            const float m1s = mcur;                 // mh[1], for i=0 later
            float mTs = mcur;                       // becomes mh[CE-2]
            #pragma unroll
            for (int i = 1; i < CE - 1; ++i) {
                float mnext;
                if (i == CE - 2) { mnext = mhT; mTs = mcur; }
                else {
                    float gv = g[i + 1];
                    mnext = fmaf(-gv, gv, gv);
                }
                g[i] = fmaf(d0, mprev, fmaf(d1, mcur, fmaf(d2, mnext, bd[i])));
                mprev = mcur;
                mcur  = mnext;
            }
            g[0]      = fmaf(d0, mleft, fmaf(d1, mh0, fmaf(d2, m1s,    bd[0])));
            g[CE - 1] = fmaf(d0, mTs,   fmaf(d1, mhT, fmaf(d2, mright, bd[CE - 1])));
        }

        // ---- transpose-store through buf[cur] (dead since its unpack) ----
        const int gw  = t * (NBLK * WPB) + gw0;
        const int row = gw >> 4, seg = gw & 15;
        float* tb = &lds[wv][cur][0];
        __builtin_amdgcn_wave_barrier();
        #pragma unroll
        for (int i = 0; i < CE; ++i) tb[lane * CE + i] = g[i];
        __builtin_amdgcn_wave_barrier();

        const float lo = 0.0001f;
        const float hi = 0.9999f;   // float(1.0 - 0.0001)
        float* op = out + (size_t)row * L + seg * SEG;
        #pragma unroll
        for (int j = 0; j < 4; ++j) {
            int f = j * 64 + lane;                    // 256 float4 = 1024 floats
            float4 v = *reinterpret_cast<float4*>(&tb[GHOST + f * 4]);
            v.x = __builtin_amdgcn_fmed3f(v.x, lo, hi);
            v.y = __builtin_amdgcn_fmed3f(v.y, lo, hi);
            v.z = __builtin_amdgcn_fmed3f(v.z, lo, hi);
            v.w = __builtin_amdgcn_fmed3f(v.w, lo, hi);
            *reinterpret_cast<float4*>(op + f * 4) = v;
        }

        // ---- swap to the prefetched buffer: wait only the 5 older loads ----
        if (t < T - 1) {
            asm volatile("s_waitcnt vmcnt(4)" ::: "memory");
            unpack(&lds[wv][cur ^ 1][0]);
            cur ^= 1;
        }
    }
}

extern "C" void kernel_launch(void* const* d_in, const int* in_sizes, int n_in,
                              void* d_out, int out_size, void* d_ws, size_t ws_size,
                              hipStream_t stream) {
    const float* drive = (const float*)d_in[0];
    const float* K     = (const float*)d_in[1];
    float* out         = (float*)d_out;
    const int rows   = in_sizes[0] / L;            // 2048
    const int gwaves = rows * (L / SEG);           // 32768 wave-segments
    const int T      = gwaves / (NBLK * WPB);      // 8 segments per wave
    cml1d_kernel<<<dim3(NBLK), dim3(TPB), 0, stream>>>(drive, K, out, T);
}

// Round 5
// 233.871 us; speedup vs baseline: 1.1313x; 1.0128x over previous
//
#include <hip/hip_runtime.h>
#include <stdint.h>

// CML1D: 15-step coupled map lattice, fp32, rows=2048, L=16384.
//   mapped = R*g*(1-g);  g' = c0*mapped[i-1] + c1*mapped[i] + c2*mapped[i+1] + BETA*d
//   (circular). out = clip(g, 1e-4, 1-1e-4) after 15 steps.
//
// R7b: identical to R7 (round-4 bench died to container infra, no signal).
//   DPP wave-shift neighbor exchange (replaces ds_bpermute).
//   - R6 post-mortem: wall stuck at ~84us across 9 and 18 waves/CU with true
//     VALU busy ~30%, LDS pack/unpack ~13us, HBM bytes ~32us -> the only
//     occupancy-invariant per-CU wall left is the per-step ds_bpermute pair:
//     64-lane LDS crossbar ops, ~30-40cy throughput each, 30/segment
//     x 128 segments/CU = 55-75us of LDS-pipe time. That's the wall.
//   - Fix: v_mov_b32_dpp wave_shr:1 / wave_shl:1 (VALU, no LDS pipe, no
//     lgkm wait). Edge lanes get bound_ctrl zeros -> ghost region only
//     (GHOST=32 > 15 contaminated cells), same as bpermute wrap-garbage.
//   - Everything else unchanged from R6: persistent waves (1024 blocks,
//     4 blocks/CU), double-buffered per-wave LDS slots, global_load_lds
//     DMA prefetch (zero VGPRs), vmcnt(4) swap, mh=fmaf(-g,g,g) with R
//     folded into taps, v_med3 clamp.

constexpr float Rc    = 3.9f;
constexpr float EPSc  = 0.3f;
constexpr float BETAc = 0.15f;
constexpr int   STEPS = 15;
constexpr int   L     = 16384;
constexpr int   CE    = 17;             // cells per lane (extended)
constexpr int   SEG   = 1024;           // valid cells per wave
constexpr int   GHOST = 32;             // ghost cells per side (>15 steps)
constexpr int   EXT   = SEG + 2*GHOST;  // 1088 = 64*CE
constexpr int   TPB   = 256;
constexpr int   WPB   = TPB / 64;       // 4 waves per block
constexpr int   NBLK  = 1024;           // 4 blocks/CU resident (LDS-capped)

// gfx9 DPP ctrl encodings (valid on CDNA/gfx950):
//   wave_shr:1 = 0x138  -> lane i reads lane i-1  (data shifts toward higher lanes)
//   wave_shl:1 = 0x130  -> lane i reads lane i+1  (data shifts toward lower lanes)
// (row_shr:N pulling from lower lanes is the classic GCN DPP scan idiom.)
constexpr int DPP_WAVE_SHL1 = 0x130;
constexpr int DPP_WAVE_SHR1 = 0x138;

__device__ __forceinline__ float dpp_shr1(float x) {   // lane i <- lane i-1
    return __int_as_float(__builtin_amdgcn_update_dpp(
        0, __float_as_int(x), DPP_WAVE_SHR1, 0xf, 0xf, true));
}
__device__ __forceinline__ float dpp_shl1(float x) {   // lane i <- lane i+1
    return __int_as_float(__builtin_amdgcn_update_dpp(
        0, __float_as_int(x), DPP_WAVE_SHL1, 0xf, 0xf, true));
}

typedef const __attribute__((address_space(1))) float gfloat;
typedef __attribute__((address_space(3))) float lfloat;

__global__ __launch_bounds__(TPB)
void cml1d_kernel(const float* __restrict__ drive,
                  const float* __restrict__ K,
                  float* __restrict__ out,
                  int T) {
    __shared__ float lds[WPB][2][EXT];   // 4*2*1088*4 = 34816 B

    const int lane = threadIdx.x & 63;
    const int wv   = threadIdx.x >> 6;
    const int gw0  = blockIdx.x * WPB + wv;   // wave-segment id; +4096 per t

    const float K0 = K[0], K1 = K[1], K2 = K[2];
    const float A  = (1.0f - BETAc) * (1.0f - EPSc);
    const float B  = (1.0f - BETAc) * EPSc;
    const float d0 = Rc * (B * K0);
    const float d1 = Rc * (A + B * K1);
    const float d2 = Rc * (B * K2);

    float g[CE], bd[CE];

    // async DMA: one segment's extended window -> LDS buf (holds no VGPRs)
    auto prefetch = [&](int gw, float* buf) {
        const int row = gw >> 4, seg = gw & 15;
        const float* base = drive + (size_t)row * L;
        const int wb = seg * SEG - GHOST;            // multiple of 32 -> wrap f4-safe
        #pragma unroll
        for (int j = 0; j < 4; ++j) {                // dest: j*1024B + lane*16B
            int idx = (wb + j * 256 + lane * 4) & (L - 1);
            __builtin_amdgcn_global_load_lds((gfloat*)(base + idx),
                                             (lfloat*)(buf + j * 256), 16, 0, 0);
        }
        int idx = (wb + 1024 + lane) & (L - 1);      // tail 64 floats, width 4
        __builtin_amdgcn_global_load_lds((gfloat*)(base + idx),
                                         (lfloat*)(buf + 1024), 4, 0, 0);
    };
    auto unpack = [&](const float* buf) {            // lane's 17 contiguous cells
        #pragma unroll
        for (int i = 0; i < CE; ++i) {
            float v = buf[lane * CE + i];
            g[i]  = v;
            bd[i] = BETAc * v;
        }
    };

    // ---- prime the pipeline ----
    prefetch(gw0, &lds[wv][0][0]);
    asm volatile("s_waitcnt vmcnt(0)" ::: "memory");
    unpack(&lds[wv][0][0]);

    int cur = 0;
    #pragma unroll 1
    for (int t = 0; t < T; ++t) {
        // issue next segment's DMA into the other buffer; flies under compute
        if (t < T - 1)
            prefetch((t + 1) * (NBLK * WPB) + gw0, &lds[wv][cur ^ 1][0]);
        __builtin_amdgcn_sched_barrier(0);   // pin DMA issue before compute

        // ---- 15 steps, register-only, no LDS, no barriers ----
        for (int s = 0; s < STEPS; ++s) {
            float mh0  = fmaf(-g[0],      g[0],      g[0]);        // g - g^2
            float mhT  = fmaf(-g[CE - 1], g[CE - 1], g[CE - 1]);
            float mleft  = dpp_shr1(mhT);   // lane i <- lane i-1 (lane 0: ghost)
            float mright = dpp_shl1(mh0);   // lane i <- lane i+1 (lane 63: ghost)

            float mprev = mh0;
            float mcur  = fmaf(-g[1], g[1], g[1]);
            const float m1s = mcur;                 // mh[1], for i=0 later
            float mTs = mcur;                       // becomes mh[CE-2]
            #pragma unroll
            for (int i = 1; i < CE - 1; ++i) {
                float mnext;
                if (i == CE - 2) { mnext = mhT; mTs = mcur; }
                else {
                    float gv = g[i + 1];
                    mnext = fmaf(-gv, gv, gv);
                }
                g[i] = fmaf(d0, mprev, fmaf(d1, mcur, fmaf(d2, mnext, bd[i])));
                mprev = mcur;
                mcur  = mnext;
            }
            g[0]      = fmaf(d0, mleft, fmaf(d1, mh0, fmaf(d2, m1s,    bd[0])));
            g[CE - 1] = fmaf(d0, mTs,   fmaf(d1, mhT, fmaf(d2, mright, bd[CE - 1])));
        }

        // ---- transpose-store through buf[cur] (dead since its unpack) ----
        const int gw  = t * (NBLK * WPB) + gw0;
        const int row = gw >> 4, seg = gw & 15;
        float* tb = &lds[wv][cur][0];
        __builtin_amdgcn_wave_barrier();
        #pragma unroll
        for (int i = 0; i < CE; ++i) tb[lane * CE + i] = g[i];
        __builtin_amdgcn_wave_barrier();

        const float lo = 0.0001f;
        const float hi = 0.9999f;   // float(1.0 - 0.0001)
        float* op = out + (size_t)row * L + seg * SEG;
        #pragma unroll
        for (int j = 0; j < 4; ++j) {
            int f = j * 64 + lane;                    // 256 float4 = 1024 floats
            float4 v = *reinterpret_cast<float4*>(&tb[GHOST + f * 4]);
            v.x = __builtin_amdgcn_fmed3f(v.x, lo, hi);
            v.y = __builtin_amdgcn_fmed3f(v.y, lo, hi);
            v.z = __builtin_amdgcn_fmed3f(v.z, lo, hi);
            v.w = __builtin_amdgcn_fmed3f(v.w, lo, hi);
            *reinterpret_cast<float4*>(op + f * 4) = v;
        }

        // ---- swap to the prefetched buffer: wait only the 5 older loads ----
        if (t < T - 1) {
            asm volatile("s_waitcnt vmcnt(4)" ::: "memory");
            unpack(&lds[wv][cur ^ 1][0]);
            cur ^= 1;
        }
    }
}

extern "C" void kernel_launch(void* const* d_in, const int* in_sizes, int n_in,
                              void* d_out, int out_size, void* d_ws, size_t ws_size,
                              hipStream_t stream) {
    const float* drive = (const float*)d_in[0];
    const float* K     = (const float*)d_in[1];
    float* out         = (float*)d_out;
    const int rows   = in_sizes[0] / L;            // 2048
    const int gwaves = rows * (L / SEG);           // 32768 wave-segments
    const int T      = gwaves / (NBLK * WPB);      // 8 segments per wave
    cml1d_kernel<<<dim3(NBLK), dim3(TPB), 0, stream>>>(drive, K, out, T);
}

// Round 6
// 232.657 us; speedup vs baseline: 1.1372x; 1.0052x over previous
//
#include <hip/hip_runtime.h>
#include <stdint.h>

// CML1D: 15-step coupled map lattice, fp32, rows=2048, L=16384.
//   mapped = R*g*(1-g);  g' = c0*mapped[i-1] + c1*mapped[i] + c2*mapped[i+1] + BETA*d
//   (circular). out = clip(g, 1e-4, 1-1e-4) after 15 steps.
//
// R8: packed-FP32 (VOP3P) stencil + high-occupancy simple structure.
//   - R7 post-mortem: VALU issue ~46-51us of 80.6 (1160 inst/segment x 32
//     segments/SIMD x ~3cy), stalls ~30us unhidden at 4 waves/SIMD (LDS-
//     capped). Prefetch machinery bought nothing vs R4 -> TLP, not SW
//     pipelining, is the right latency-hiding tool here.
//   - Packed stencil via stride-split pairs: P[j] = (c[j], c[j+4]), j=0..4
//     (CE=9 cells/lane, one dup slot c[4] kept bitwise-consistent). A 1-cell
//     stencil shift becomes a 1-step shift in j -> all v_pk_fma_f32 operands
//     are aligned register pairs; only the two seam pairs need assembly
//     (2 DPP wave-shifts + 2 movs). mh = (-p)*p + p via neg_lo/neg_hi:
//     single-rounded, bit-identical to R7's scalar fmaf(-g,g,g).
//     ~26 VALU/step vs R7's 70 for ~2x the cells per instruction.
//   - Occupancy: SEG=512 -> EXT=576 -> 9216 B LDS/block; no persistence, no
//     double buffer (at 8 waves/SIMD the DMA wait hides under other waves).
//     __launch_bounds__(256,8) pins VGPR <= 64 (the 8-waves/SIMD cliff).
//   - I/O unchanged in spirit: global_load_lds DMA in (2x w16 + 1x w4),
//     LDS transpose, float4 + v_med3 clamped stores out.

constexpr float Rc    = 3.9f;
constexpr float EPSc  = 0.3f;
constexpr float BETAc = 0.15f;
constexpr int   STEPS = 15;
constexpr int   L     = 16384;
constexpr int   CE    = 9;              // cells per lane (extended)
constexpr int   HALF  = 4;              // pair stride: P[j]=(c[j],c[j+HALF])
constexpr int   NP    = HALF + 1;       // 5 pairs (c[4] duplicated)
constexpr int   SEG   = 512;            // valid cells per wave
constexpr int   GHOST = 32;             // > 15 steps of edge contamination
constexpr int   EXT   = SEG + 2*GHOST;  // 576 = 64*CE
constexpr int   TPB   = 256;
constexpr int   WPB   = TPB / 64;       // 4 waves per block
constexpr int   SPR   = L / SEG;        // 32 segments per row

// gfx9 DPP ctrl (validated on HW in R7: same absmax, passed):
//   wave_shr:1 = lane i <- lane i-1 ; wave_shl:1 = lane i <- lane i+1.
constexpr int DPP_WAVE_SHL1 = 0x130;
constexpr int DPP_WAVE_SHR1 = 0x138;

__device__ __forceinline__ float dpp_shr1(float x) {   // lane i <- lane i-1
    return __int_as_float(__builtin_amdgcn_update_dpp(
        0, __float_as_int(x), DPP_WAVE_SHR1, 0xf, 0xf, true));
}
__device__ __forceinline__ float dpp_shl1(float x) {   // lane i <- lane i+1
    return __int_as_float(__builtin_amdgcn_update_dpp(
        0, __float_as_int(x), DPP_WAVE_SHL1, 0xf, 0xf, true));
}

// VOP3P packed fp32 (CDNA2+; register pairs, even-aligned by the backend).
__device__ __forceinline__ float2 pk_mul(float2 a, float2 b) {
    float2 d;
    asm("v_pk_mul_f32 %0, %1, %2" : "=v"(d) : "v"(a), "v"(b));
    return d;
}
__device__ __forceinline__ float2 pk_fma(float2 a, float2 b, float2 c) {
    float2 d;
    asm("v_pk_fma_f32 %0, %1, %2, %3" : "=v"(d) : "v"(a), "v"(b), "v"(c));
    return d;
}
__device__ __forceinline__ float2 pk_fma_na(float2 a, float2 b, float2 c) {
    // d = (-a)*b + c on both halves (single-rounded fma)
    float2 d;
    asm("v_pk_fma_f32 %0, %1, %2, %3 neg_lo:[1,0,0] neg_hi:[1,0,0]"
        : "=v"(d) : "v"(a), "v"(b), "v"(c));
    return d;
}

typedef const __attribute__((address_space(1))) float gfloat;
typedef __attribute__((address_space(3))) float lfloat;

__global__ __launch_bounds__(TPB, 8)   // 8 waves/EU -> VGPR capped at 64
void cml1d_kernel(const float* __restrict__ drive,
                  const float* __restrict__ K,
                  float* __restrict__ out) {
    __shared__ float lds[WPB][EXT];    // 4*576*4 = 9216 B

    const int lane = threadIdx.x & 63;
    const int wv   = threadIdx.x >> 6;
    const int gw   = blockIdx.x * WPB + wv;
    const int row  = gw >> 5;                // /SPR
    const int seg  = gw & (SPR - 1);
    const float* base = drive + (size_t)row * L;
    const int wb = seg * SEG - GHOST;        // mult of 32 -> wrap float4-safe

    // ---- DMA the extended window into this wave's LDS slot (issued first) --
    float* buf = &lds[wv][0];
    #pragma unroll
    for (int j = 0; j < 2; ++j) {            // dest: j*1024B + lane*16B
        int idx = (wb + j * 256 + lane * 4) & (L - 1);
        __builtin_amdgcn_global_load_lds((gfloat*)(base + idx),
                                         (lfloat*)(buf + j * 256), 16, 0, 0);
    }
    {
        int idx = (wb + 512 + lane) & (L - 1);   // tail 64 floats, width 4
        __builtin_amdgcn_global_load_lds((gfloat*)(base + idx),
                                         (lfloat*)(buf + 512), 4, 0, 0);
    }

    // constants while the DMA flies
    const float K0 = K[0], K1 = K[1], K2 = K[2];
    const float A  = (1.0f - BETAc) * (1.0f - EPSc);
    const float B  = (1.0f - BETAc) * EPSc;
    const float d0 = Rc * (B * K0);
    const float d1 = Rc * (A + B * K1);
    const float d2 = Rc * (B * K2);
    const float2 D0 = make_float2(d0, d0);
    const float2 D1 = make_float2(d1, d1);
    const float2 D2 = make_float2(d2, d2);
    const float2 B2 = make_float2(BETAc, BETAc);

    asm volatile("s_waitcnt vmcnt(0)" ::: "memory");

    // ---- unpack into stride-split pairs: P[j] = (c[j], c[j+4]) ----
    // (lane*9 stride: 9 coprime 32 -> 2 lanes/bank, conflict-free)
    float2 P[NP], BD[NP];
    #pragma unroll
    for (int j = 0; j < NP; ++j) {
        P[j]  = make_float2(buf[lane * CE + j], buf[lane * CE + j + HALF]);
        BD[j] = pk_mul(B2, P[j]);
    }

    // ---- 15 steps, register-only, all-aligned packed ops ----
    for (int s = 0; s < STEPS; ++s) {
        float2 MH[NP];
        #pragma unroll
        for (int j = 0; j < NP; ++j)
            MH[j] = pk_fma_na(P[j], P[j], P[j]);       // mh = p - p^2

        const float mleft  = dpp_shr1(MH[NP - 1].y);   // lane-1's mh[8] = mh[-1]
        const float mright = dpp_shl1(MH[0].x);        // lane+1's mh[0] = mh[9]
        const float2 MHm1_0 = make_float2(mleft, MH[HALF - 1].x); // (mh[-1], mh[3])
        const float2 MHp1_T = make_float2(MH[1].y, mright);       // (mh[5],  mh[9])

        #pragma unroll
        for (int j = 0; j < NP; ++j) {                 // G[j] = (g'[j], g'[j+4])
            float2 a = (j == 0)      ? MHm1_0 : MH[j - 1];
            float2 b = (j == NP - 1) ? MHp1_T : MH[j + 1];
            P[j] = pk_fma(D0, a, pk_fma(D1, MH[j], pk_fma(D2, b, BD[j])));
        }
    }

    // ---- pairs -> LDS -> coalesced float4 clamped stores of middle 512 ----
    __builtin_amdgcn_wave_barrier();
    #pragma unroll
    for (int j = 0; j < NP; ++j) {
        buf[lane * CE + j]        = P[j].x;            // c[0..4]
        buf[lane * CE + j + HALF] = P[j].y;            // c[4..8] (c4 dup, equal)
    }
    __builtin_amdgcn_wave_barrier();

    const float lo = 0.0001f;
    const float hi = 0.9999f;   // float(1.0 - 0.0001)
    float* op = out + (size_t)row * L + seg * SEG;
    #pragma unroll
    for (int j = 0; j < 2; ++j) {
        int f = j * 64 + lane;                         // 128 float4 = 512 floats
        float4 v = *reinterpret_cast<float4*>(&buf[GHOST + f * 4]);
        v.x = __builtin_amdgcn_fmed3f(v.x, lo, hi);
        v.y = __builtin_amdgcn_fmed3f(v.y, lo, hi);
        v.z = __builtin_amdgcn_fmed3f(v.z, lo, hi);
        v.w = __builtin_amdgcn_fmed3f(v.w, lo, hi);
        *reinterpret_cast<float4*>(op + f * 4) = v;
    }
}

extern "C" void kernel_launch(void* const* d_in, const int* in_sizes, int n_in,
                              void* d_out, int out_size, void* d_ws, size_t ws_size,
                              hipStream_t stream) {
    const float* drive = (const float*)d_in[0];
    const float* K     = (const float*)d_in[1];
    float* out         = (float*)d_out;
    const int rows   = in_sizes[0] / L;              // 2048
    const int blocks = rows * SPR / WPB;             // 16384
    cml1d_kernel<<<dim3(blocks), dim3(TPB), 0, stream>>>(drive, K, out);
}